// Round 8
// baseline (303.488 us; speedup 1.0000x reference)
//
#include <hip/hip_runtime.h>

// ---------------------------------------------------------------------------
// SelfAttentionLayer: out[b,s,c*16+h] = softmax_k( (q.k)/32 masked ) @ v
// R7: fused kernel, phase 1 rewritten as a BARRIER-FREE register GEMM.
// A/B MFMA fragments (16B/lane contiguous) load straight from global
// (L2-resident X[b] 512KB + W-slice 96KB), ping-pong prefetched one 32-k
// chunk ahead. No LDS, no __syncthreads in the K-loop -> no drain stalls,
// LDS pipe freed. Phase 2 = R6-verified MFMA attention.
// ---------------------------------------------------------------------------

typedef unsigned short u16;
typedef unsigned int u32;
typedef __attribute__((ext_vector_type(8))) short short8;
typedef __attribute__((ext_vector_type(4))) short short4v;
typedef __attribute__((ext_vector_type(4))) float floatx4;

#if __has_builtin(__builtin_amdgcn_mfma_f32_16x16x16bf16_1k)
#define MFMA16(A, B, C) __builtin_amdgcn_mfma_f32_16x16x16bf16_1k(A, B, C, 0, 0, 0)
#elif __has_builtin(__builtin_amdgcn_mfma_f32_16x16x16_bf16)
#define MFMA16(A, B, C) __builtin_amdgcn_mfma_f32_16x16x16_bf16(A, B, C, 0, 0, 0)
#else
__device__ __forceinline__ floatx4 mfma16_asm(short4v a, short4v b, floatx4 c) {
  floatx4 d;
  asm volatile("v_mfma_f32_16x16x16_bf16 %0, %1, %2, %3"
               : "=v"(d) : "v"(a), "v"(b), "v"(c));
  return d;
}
#define MFMA16(A, B, C) mfma16_asm(A, B, C)
#endif

#if __has_builtin(__builtin_amdgcn_exp2f)
#define EXP2(x) __builtin_amdgcn_exp2f(x)
#else
#define EXP2(x) __expf((x) * 0.6931471805599453f)
#endif

#define QSCALE 0.045084220f  // log2(e)/32, folded into Q

__device__ __forceinline__ u16 f2bf(float f) {
  union { float f; u32 u; } x; x.f = f;
  u32 r = x.u + 0x7fffu + ((x.u >> 16) & 1u);  // RNE
  return (u16)(r >> 16);
}
__device__ __forceinline__ float bf2f(u16 u) {
  union { u32 u; float f; } x; x.u = ((u32)u) << 16;
  return x.f;
}

#define GK 1024
#define QKS 20   // Qs/Ks row stride (u16): 8B-aligned frags, conflict-free
#define VTS 264  // Vt row stride (u16): 2-way-max banks (free)

// ---------------------------------------------------------------------------
// Merged cast f32 -> bf16: X (8192 blocks), Wq/Wk/Wv (1024 blocks each)
// ---------------------------------------------------------------------------
__global__ __launch_bounds__(256) void cast_all(const float* __restrict__ x,
                                                const float* __restrict__ wq,
                                                const float* __restrict__ wk,
                                                const float* __restrict__ wv,
                                                u16* __restrict__ XB,
                                                u16* __restrict__ WB) {
  int bid = blockIdx.x;
  const float* src; u16* dst; int off;
  if (bid < 8192)       { src = x;  dst = XB;                 off = bid; }
  else if (bid < 9216)  { src = wq; dst = WB;                 off = bid - 8192; }
  else if (bid < 10240) { src = wk; dst = WB + 1024 * 1024;   off = bid - 9216; }
  else                  { src = wv; dst = WB + 2 * 1024 * 1024; off = bid - 10240; }
  int i = (off * 256 + threadIdx.x) * 4;
  float4 v = *(const float4*)(src + i);
  u32 lo = (u32)f2bf(v.x) | ((u32)f2bf(v.y) << 16);
  u32 hi = (u32)f2bf(v.z) | ((u32)f2bf(v.w) << 16);
  uint2 o; o.x = lo; o.y = hi;
  *(uint2*)(dst + i) = o;
}

// ---------------------------------------------------------------------------
// Attn kt-loop (R5/R6-verified): S^T = MFMA(K, Qscaled); p = exp2(st)
// trunc-packed via v_perm; l via MFMA(ones,p); O^T += MFMA(V^T,p)
// ---------------------------------------------------------------------------
template <bool MASKED>
__device__ __forceinline__ void attn_loop(const u16* __restrict__ Ks,
                                          const u16* __restrict__ Vt,
                                          const short4v* bq, const float* mqv,
                                          const float* m_s,
                                          floatx4* oacc, floatx4* lacc,
                                          int col, int quad) {
  const short4v ones = {(short)0x3F80, (short)0x3F80, (short)0x3F80, (short)0x3F80};
#pragma unroll 4
  for (int kt = 0; kt < 16; kt++) {
    const int kb = kt * 16;
    short4v ak = *(const short4v*)(Ks + (kb + col) * QKS + quad * 4);
    short4v av = *(const short4v*)(Vt + col * VTS + kb + quad * 4);
    float mk[4];
    if (MASKED) {
#pragma unroll
      for (int i = 0; i < 4; i++) mk[i] = m_s[kb + quad * 4 + i];
    }
#pragma unroll
    for (int qt = 0; qt < 4; qt++) {
      floatx4 z = {0.f, 0.f, 0.f, 0.f};
      floatx4 st = MFMA16(ak, bq[qt], z);
      float e[4];
#pragma unroll
      for (int i = 0; i < 4; i++) {
        e[i] = EXP2(st[i]);
        if (MASKED) e[i] = (mqv[qt] * mk[i] > 0.f) ? e[i] : 0.f;
      }
      union { u32 u[2]; short4v s; } pk;
      pk.u[0] = __builtin_amdgcn_perm(__float_as_uint(e[1]), __float_as_uint(e[0]), 0x07060302u);
      pk.u[1] = __builtin_amdgcn_perm(__float_as_uint(e[3]), __float_as_uint(e[2]), 0x07060302u);
      lacc[qt] = MFMA16(ones, pk.s, lacc[qt]);
      oacc[qt] = MFMA16(av, pk.s, oacc[qt]);
    }
  }
}

// ---------------------------------------------------------------------------
// Fused kernel. Block = (c = bid>>5, b = bid&31); XCD = bid&7 = b&7 so the
// 4 X[b] slices per XCD (2 MB) stay L2-resident.
// Phase 1: register GEMM, no LDS, no barriers. Wave w owns m-strip
// [64w,64w+64): acc[4 mt][3 nt] (nt: 0=Q,1=K,2=V). Fragments load direct:
//   A[m=lane&15][k=quad*8+j] -> one dwordx4 from X row (m-strip)
//   B[n=lane&15][k=quad*8+j] -> one dwordx4 from W row (head slice)
// ping-pong prefetch one 32-k chunk ahead; compiler inserts vmcnt only.
// Phase 2: Q,K (stride-20) + V^T (stride-264) through LDS -> attn_loop.
// ---------------------------------------------------------------------------
__global__ __launch_bounds__(256) void fused_qkv_attn(const u16* __restrict__ XB,
                                                      const u16* __restrict__ WB,
                                                      const float* __restrict__ mask,
                                                      float* __restrict__ out) {
  __shared__ u16 smem[14976];   // Qs@0 [256*20], Ks@5120 [256*20],
                                // Vt@10240 [16*264], l_s@14464 (256 f32)
                                // ot (16*257 f32) overlays Qs+Ks in epilogue
  __shared__ float m_s[256];

  const int bid = blockIdx.x;
  const int b = bid & 31;
  const int c = bid >> 5;
  const int t = threadIdx.x;
  const int wave = t >> 6;
  const int lane = t & 63;
  const int col = lane & 15;
  const int quad = lane >> 4;

  float mv = mask[b * 256 + t];
  m_s[t] = mv;
  const int allones = __syncthreads_and(mv > 0.f);

  // ---------------- phase 1: barrier-free register GEMM ----------------
  // per-lane fragment bases
  const u16* Xw = XB + ((size_t)b * 256 + wave * 64) * GK;   // wave m-strip
  const int k_l = quad * 8;                                   // k offset (elems)

  const u16* arow[4];
#pragma unroll
  for (int mt = 0; mt < 4; mt++)
    arow[mt] = Xw + (size_t)(mt * 16 + col) * GK + k_l;
  const u16* brow[3];
#pragma unroll
  for (int nt = 0; nt < 3; nt++)
    brow[nt] = WB + (size_t)(nt * 1024 + c * 16 + col) * GK + k_l;

  floatx4 acc[4][3] = {};
  short8 ax[2][4], bx[2][3];

#pragma unroll
  for (int mt = 0; mt < 4; mt++) ax[0][mt] = *(const short8*)(arow[mt]);
#pragma unroll
  for (int nt = 0; nt < 3; nt++) bx[0][nt] = *(const short8*)(brow[nt]);

#pragma unroll 4
  for (int i = 0; i < 32; i++) {
    const int cur = i & 1, nxt = cur ^ 1;
    if (i < 31) {
      const int kc = (i + 1) * 32;
#pragma unroll
      for (int mt = 0; mt < 4; mt++) ax[nxt][mt] = *(const short8*)(arow[mt] + kc);
#pragma unroll
      for (int nt = 0; nt < 3; nt++) bx[nxt][nt] = *(const short8*)(brow[nt] + kc);
    }
#pragma unroll
    for (int mt = 0; mt < 4; mt++)
#pragma unroll
      for (int nt = 0; nt < 3; nt++)
        acc[mt][nt] = __builtin_amdgcn_mfma_f32_16x16x32_bf16(ax[cur][mt], bx[cur][nt], acc[mt][nt], 0, 0, 0);
  }

  // ---------------- Q/K/V -> LDS (per-wave-exclusive regions) ----------------
  u16* Qs = smem;               // [256][QKS]
  u16* Ks = smem + 5120;        // [256][QKS]
  u16* Vt = smem + 10240;       // [16][VTS]
  float* l_s = (float*)(smem + 14464);

  // C/D layout: row = m-base + quad*4 + r, col(head feature) = lane&15
#pragma unroll
  for (int mt = 0; mt < 4; mt++) {
    const int row = wave * 64 + mt * 16 + quad * 4;
#pragma unroll
    for (int r = 0; r < 4; r++) {
      Qs[(row + r) * QKS + col] = f2bf(acc[mt][0][r] * QSCALE);
      Ks[(row + r) * QKS + col] = f2bf(acc[mt][1][r]);
      Vt[col * VTS + row + r] = f2bf(acc[mt][2][r]);
    }
  }
  __syncthreads();

  // ---------------- phase 2: attention ----------------
  const int q0 = wave * 64;

  short4v bq[4];
#pragma unroll
  for (int qt = 0; qt < 4; qt++)
    bq[qt] = *(const short4v*)(Qs + (q0 + qt * 16 + col) * QKS + quad * 4);

  float mqv[4];
#pragma unroll
  for (int qt = 0; qt < 4; qt++) mqv[qt] = m_s[q0 + qt * 16 + col];

  floatx4 oacc[4] = {};
  floatx4 lacc[4] = {};

  if (allones)
    attn_loop<false>(Ks, Vt, bq, mqv, m_s, oacc, lacc, col, quad);
  else
    attn_loop<true>(Ks, Vt, bq, mqv, m_s, oacc, lacc, col, quad);

  __syncthreads();  // all waves out of attn_loop before ot overlays Qs/Ks
  float* ot = (float*)smem;  // [16][257] f32 = 16.4 KB, inside Qs+Ks (20 KB)

#pragma unroll
  for (int qt = 0; qt < 4; qt++) {
    if (quad == 0) l_s[q0 + qt * 16 + col] = lacc[qt][0];
#pragma unroll
    for (int r = 0; r < 4; r++)
      ot[(quad * 4 + r) * 257 + q0 + qt * 16 + col] = oacc[qt][r];
  }
  __syncthreads();

  // epilogue: thread t owns q-row t; 64B coalesced f32 store
  float l = l_s[t];
  float* op = out + ((size_t)b * 256 + t) * 1024 + c * 16;
  float o[16];
  if (allones || l > 0.f) {
    float inv = 1.0f / l;
#pragma unroll
    for (int h = 0; h < 16; h++) o[h] = ot[h * 257 + t] * inv;
  } else {
    // fully-masked row: reference softmax of uniform -1e9 -> mean of V
#pragma unroll
    for (int h = 0; h < 16; h++) o[h] = 0.f;
    for (int k = 0; k < 256; k++)
#pragma unroll
      for (int h = 0; h < 16; h++) o[h] += bf2f(Vt[h * VTS + k]);
#pragma unroll
    for (int h = 0; h < 16; h++) o[h] *= (1.0f / 256.0f);
  }
#pragma unroll
  for (int g = 0; g < 4; g++) {
    float4 r;
    r.x = o[g * 4 + 0]; r.y = o[g * 4 + 1]; r.z = o[g * 4 + 2]; r.w = o[g * 4 + 3];
    *(float4*)(op + g * 4) = r;
  }
}

// ---------------------------------------------------------------------------
// Launch
// ---------------------------------------------------------------------------
extern "C" void kernel_launch(void* const* d_in, const int* in_sizes, int n_in,
                              void* d_out, int out_size, void* d_ws, size_t ws_size,
                              hipStream_t stream) {
  const float* x    = (const float*)d_in[0];  // [32,256,1024]
  const float* mask = (const float*)d_in[1];  // [32,256]
  const float* Wq   = (const float*)d_in[2];  // [1024,1024]
  const float* Wk   = (const float*)d_in[3];
  const float* Wv   = (const float*)d_in[4];
  float* out = (float*)d_out;

  u16* XB = (u16*)d_ws;                       // [8192][1024] bf16
  u16* WB = XB + (size_t)8192 * 1024;         // [3072][1024] (Wq,Wk,Wv stacked)

  cast_all<<<11264, 256, 0, stream>>>(x, Wq, Wk, Wv, XB, WB);
  fused_qkv_attn<<<2048, 256, 0, stream>>>(XB, WB, mask, out);
}